// Round 5
// baseline (385.189 us; speedup 1.0000x reference)
//
#include <hip/hip_runtime.h>
#include <math.h>

#define B 8
#define NPTS 4096
#define QPT 8           // queries per thread in chamfer
#define THREADS 256

// ws layout: [partial: 2*B*S*NPTS f][sums32: 32 f][h1p: 64*256 f][nlls: 8 f][cnt: 33 u32]
// partial[((dir*B+b)*S + split)*NPTS + q]
// sums32[(dir*B+b)*2 + {0:min,1:soft}]  (atomicAdd by 2 reducers each — commutative, bit-exact)
// cnt[0..31]: per-(dir,b,qchunk) split-completion tickets; cnt[32]: global ticket

__device__ __forceinline__ void final_combine(
    const float* sums32, const float* nlls, const float* w, float* out) {
  float chamfer = 0.f, prec = 0.f, rec = 0.f, dsw = 0.f, dom = 0.f;
  for (int b = 0; b < B; ++b) {
    float sa  = sums32[(0 * B + b) * 2 + 0];
    float ssa = sums32[(0 * B + b) * 2 + 1];
    float sb  = sums32[(1 * B + b) * 2 + 0];
    float ssb = sums32[(1 * B + b) * 2 + 1];
    float ma = sa / 4096.f, mb = sb / 4096.f;
    float p = ssa / 4096.f, r = ssb / 4096.f;
    chamfer += ma + mb;
    prec += p; rec += r;
    float f_i = 2.f * p * r / (p + r + 1e-8f);
    float loss_i = ma + mb + 0.1f * (1.f - f_i);
    dsw += w[b] * loss_i;
    dom += nlls[b];
  }
  chamfer *= (1.f / B); prec *= (1.f / B); rec *= (1.f / B);
  dsw *= (1.f / B); dom *= (1.f / B);
  float fscore = 2.f * prec * rec / (prec + rec + 1e-8f);
  float task = chamfer + 0.1f * (1.f - fscore);
  out[0] = 1.0f * task + 0.1f * dom + dsw;
}

// ======== D1: 64 MLP-L1 blocks; block 0 also zeros sums32 + tickets ======
__global__ __launch_bounds__(THREADS) void k_init_l1(
    const float* __restrict__ x, const float* __restrict__ W1,
    float* __restrict__ h1p, float* __restrict__ sums32,
    unsigned int* __restrict__ cnt) {
  int id = blockIdx.x, tid = threadIdx.x;
  if (id == 0) {
    if (tid < 32) sums32[tid] = 0.f;
    if (tid < 33) cnt[tid] = 0u;
  }
  int b = id >> 3, kc = id & 7;
  __shared__ float xs[64];
  if (tid < 64) xs[tid] = x[b * 512 + kc * 64 + tid];
  __syncthreads();
  float acc = 0.f;
  const float* w = W1 + (size_t)(kc * 64) * 256 + tid;
#pragma unroll 8
  for (int k = 0; k < 64; ++k) acc = fmaf(xs[k], w[k * 256], acc);
  h1p[(b * 8 + kc) * 256 + tid] = acc;
}

// ======== D2: fused chamfer + ticketed reduce + MLP L2/L3 + final ========
template<int S, int LOG2S>
__global__ __launch_bounds__(THREADS, 4) void k_fused(
    const float* __restrict__ pred, const float* __restrict__ targ,
    const float* __restrict__ h1p, const float* __restrict__ b1,
    const float* __restrict__ W2, const float* __restrict__ b2,
    const float* __restrict__ W3, const float* __restrict__ b3,
    const int* __restrict__ labels, const float* __restrict__ wgt,
    float* __restrict__ partial, float* __restrict__ sums32,
    float* __restrict__ nlls, unsigned int* __restrict__ cnt,
    float* __restrict__ out) {
  constexpr int REFS = NPTS / S;
  int id = blockIdx.x, tid = threadIdx.x;

  __shared__ float4 sbuf4[1040];       // 16.6 KB shared arena
  float* sbuf = (float*)sbuf4;
  __shared__ unsigned int sflag;

  if (id < 32 * S) {
    // ---------------- chamfer split-partial mins ----------------
    int cid = id;
    int split  = cid & (S - 1);
    int qchunk = (cid >> LOG2S) & 1;
    int b      = (cid >> (LOG2S + 1)) & 7;
    int dir    = cid >> (LOG2S + 4);
    const float* qp = dir ? targ : pred;
    const float* rp = dir ? pred : targ;

    float4* refs = sbuf4;
    const float* rb = rp + ((size_t)b * NPTS + (size_t)split * REFS) * 3;
    for (int i = tid; i < REFS; i += THREADS) {
      float xx = rb[i * 3 + 0], yy = rb[i * 3 + 1], zz = rb[i * 3 + 2];
      refs[i] = make_float4(xx, yy, zz, 0.5f * (xx * xx + yy * yy + zz * zz));
    }
    __syncthreads();

    const float* qb = qp + (size_t)b * NPTS * 3;
    int q0 = qchunk * (QPT * THREADS) + tid;
    float qx[QPT], qy[QPT], qz[QPT], vmin[QPT];
#pragma unroll
    for (int i = 0; i < QPT; ++i) {
      int q = q0 + i * THREADS;
      qx[i] = qb[q * 3 + 0];
      qy[i] = qb[q * 3 + 1];
      qz[i] = qb[q * 3 + 2];
      vmin[i] = 3.4e38f;
    }

    for (int j = 0; j < REFS; j += 4) {
      float4 t0 = refs[j + 0], t1 = refs[j + 1];
      float4 t2 = refs[j + 2], t3 = refs[j + 3];
      // pin tiles in VGPRs — stop the compiler rematerializing LDS reads per query
      asm volatile("" : "+v"(t0.x), "+v"(t0.y), "+v"(t0.z), "+v"(t0.w),
                        "+v"(t1.x), "+v"(t1.y), "+v"(t1.z), "+v"(t1.w),
                        "+v"(t2.x), "+v"(t2.y), "+v"(t2.z), "+v"(t2.w),
                        "+v"(t3.x), "+v"(t3.y), "+v"(t3.z), "+v"(t3.w));
#pragma unroll
      for (int i = 0; i < QPT; ++i) {
        float s0 = fmaf(-qx[i], t0.x, fmaf(-qy[i], t0.y, fmaf(-qz[i], t0.z, t0.w)));
        float s1 = fmaf(-qx[i], t1.x, fmaf(-qy[i], t1.y, fmaf(-qz[i], t1.z, t1.w)));
        float s2 = fmaf(-qx[i], t2.x, fmaf(-qy[i], t2.y, fmaf(-qz[i], t2.z, t2.w)));
        float s3 = fmaf(-qx[i], t3.x, fmaf(-qy[i], t3.y, fmaf(-qz[i], t3.z, t3.w)));
        vmin[i] = fminf(fminf(vmin[i], fminf(s0, s1)), fminf(s2, s3));
      }
    }

    size_t base = (((size_t)dir * B + b) * S + split) * NPTS;
#pragma unroll
    for (int i = 0; i < QPT; ++i) {
      float qn = fmaf(qx[i], qx[i], fmaf(qy[i], qy[i], qz[i] * qz[i]));
      partial[base + q0 + i * THREADS] = fmaf(2.f, vmin[i], qn);
    }

    // ---- ticket: last split of this (dir,b,qchunk) becomes its reducer
    __threadfence();
    if (tid == 0) {
      unsigned int old = atomicAdd(&cnt[(dir * 8 + b) * 2 + qchunk], 1u);
      sflag = (old == (unsigned int)(S - 1)) ? 1u : 0u;
    }
    __syncthreads();
    if (!sflag) return;

    // ---------------- reducer for (dir,b,qchunk) ----------------
    __threadfence();   // acquire: see all splits' partials
    size_t pb = (size_t)(dir * B + b) * S * NPTS;
    float s_min = 0.f, s_soft = 0.f;
#pragma unroll
    for (int u = 0; u < QPT; ++u) {
      int q = qchunk * (QPT * THREADS) + u * THREADS + tid;
      float m = 3.4e38f;
      for (int s = 0; s < S; ++s)
        m = fminf(m, partial[pb + (size_t)s * NPTS + q]);
      s_min  += m;
      s_soft += __expf(-5000.0f * m);   // 1/(2*sigma^2) = 5000
    }
    for (int off = 32; off > 0; off >>= 1) {
      s_min  += __shfl_down(s_min,  off);
      s_soft += __shfl_down(s_soft, off);
    }
    int wave = tid >> 6, lane = tid & 63;
    float* red = sbuf + 4160;
    if (lane == 0) { red[wave * 2] = s_min; red[wave * 2 + 1] = s_soft; }
    __syncthreads();
    if (tid == 0) {
      float a = 0.f, c = 0.f;
      for (int w = 0; w < 4; ++w) { a += red[w * 2]; c += red[w * 2 + 1]; }
      atomicAdd(&sums32[(dir * B + b) * 2 + 0], a);
      atomicAdd(&sums32[(dir * B + b) * 2 + 1], c);
      __threadfence();
      unsigned int old = atomicAdd(&cnt[32], 1u);
      sflag = (old == 32u) ? 1u : 0u;    // 33 participants: 32 reducers + 1 MLP
    }
    __syncthreads();
    if (sflag && tid == 0) { __threadfence(); final_combine(sums32, nlls, wgt, out); }
    return;
  }

  // ---------------- MLP block (id == 32*S): L2 + L3 + NLL ----------------
  float* h1s = sbuf;                 // 2048
  float* pp  = sbuf + 2048;          // 2048
  float* h2s = sbuf;                 // aliases h1s (dead after L2 partials)
  float* lgs = sbuf + 4096;          // 48

  for (int i = tid; i < 2048; i += THREADS) {
    int bb = i >> 8, j = i & 255;
    float a = b1[j];
#pragma unroll
    for (int kc = 0; kc < 8; ++kc) a += h1p[(bb * 8 + kc) * 256 + j];
    h1s[i] = fmaxf(a, 0.f);
  }
  __syncthreads();
  {
    int j = tid & 127, half = tid >> 7;
    float acc[8];
#pragma unroll
    for (int bb = 0; bb < 8; ++bb) acc[bb] = 0.f;
    const float* w = W2 + (size_t)(half * 128) * 128 + j;
    for (int k = 0; k < 128; ++k) {
      float wv = w[k * 128];
      int kk = half * 128 + k;
#pragma unroll
      for (int bb = 0; bb < 8; ++bb)
        acc[bb] = fmaf(h1s[bb * 256 + kk], wv, acc[bb]);
    }
    __syncthreads();   // h1s reads done before pp writes overlap region? (pp separate; sync for h2s alias safety below)
#pragma unroll
    for (int bb = 0; bb < 8; ++bb) pp[(half * 8 + bb) * 128 + j] = acc[bb];
  }
  __syncthreads();
  for (int i = tid; i < 1024; i += THREADS) {
    int bb = i >> 7, j = i & 127;
    float a = b2[j] + pp[(0 * 8 + bb) * 128 + j] + pp[(1 * 8 + bb) * 128 + j];
    h2s[i] = fmaxf(a, 0.f);
  }
  __syncthreads();
  if (tid < 48) {
    int bb = tid / 6, d = tid % 6;
    float acc = b3[d];
#pragma unroll 8
    for (int k = 0; k < 128; ++k) acc = fmaf(h2s[bb * 128 + k], W3[k * 6 + d], acc);
    lgs[tid] = acc;
  }
  __syncthreads();
  if (tid < 8) {
    int bb = tid;
    float mx = lgs[bb * 6];
    for (int d = 1; d < 6; ++d) mx = fmaxf(mx, lgs[bb * 6 + d]);
    float se = 0.f;
    for (int d = 0; d < 6; ++d) se += __expf(lgs[bb * 6 + d] - mx);
    int lab = labels[bb];
    nlls[bb] = -(lgs[bb * 6 + lab] - mx - __logf(se));
  }
  __syncthreads();
  __threadfence();
  if (tid == 0) {
    unsigned int old = atomicAdd(&cnt[32], 1u);
    sflag = (old == 32u) ? 1u : 0u;
  }
  __syncthreads();
  if (sflag && tid == 0) { __threadfence(); final_combine(sums32, nlls, wgt, out); }
}

template<int S, int LOG2S>
static void run_pipeline(const float* pred, const float* targ, const float* x,
                         const float* wgt, const float* W1, const float* b1,
                         const float* W2, const float* b2, const float* W3,
                         const float* b3, const int* labels, float* out,
                         char* ws, hipStream_t stream) {
  float* partial = (float*)ws;
  float* sums32  = partial + (size_t)2 * B * S * NPTS;
  float* h1p     = sums32 + 32;
  float* nlls    = h1p + 64 * 256;
  unsigned int* cnt = (unsigned int*)(nlls + 8);

  hipLaunchKernelGGL(k_init_l1, dim3(64), dim3(THREADS), 0, stream,
                     x, W1, h1p, sums32, cnt);
  hipLaunchKernelGGL((k_fused<S, LOG2S>), dim3(32 * S + 1), dim3(THREADS), 0,
                     stream, pred, targ, h1p, b1, W2, b2, W3, b3, labels, wgt,
                     partial, sums32, nlls, cnt, out);
}

extern "C" void kernel_launch(void* const* d_in, const int* in_sizes, int n_in,
                              void* d_out, int out_size, void* d_ws, size_t ws_size,
                              hipStream_t stream) {
  const float* pred   = (const float*)d_in[0];
  const float* targ   = (const float*)d_in[1];
  const float* x      = (const float*)d_in[2];
  const float* wgt    = (const float*)d_in[3];
  const float* W1     = (const float*)d_in[4];
  const float* b1     = (const float*)d_in[5];
  const float* W2     = (const float*)d_in[6];
  const float* b2     = (const float*)d_in[7];
  const float* W3     = (const float*)d_in[8];
  const float* b3     = (const float*)d_in[9];
  const int*   labels = (const int*)d_in[10];
  float* out = (float*)d_out;
  char* ws = (char*)d_ws;

  auto need = [](int S) {
    return ((size_t)2 * B * S * NPTS + 32 + 64 * 256 + 8) * sizeof(float)
           + 33 * sizeof(unsigned int);
  };
  if (ws_size >= need(64))
    run_pipeline<64, 6>(pred, targ, x, wgt, W1, b1, W2, b2, W3, b3, labels,
                        out, ws, stream);
  else if (ws_size >= need(32))
    run_pipeline<32, 5>(pred, targ, x, wgt, W1, b1, W2, b2, W3, b3, labels,
                        out, ws, stream);
  else
    run_pipeline<16, 4>(pred, targ, x, wgt, W1, b1, W2, b2, W3, b3, labels,
                        out, ws, stream);
}

// Round 6
// 126.945 us; speedup vs baseline: 3.0343x; 3.0343x over previous
//
#include <hip/hip_runtime.h>
#include <math.h>

#define B 8
#define NPTS 4096
#define SPLITS 32
#define LOG2S 5
#define REFS (NPTS / SPLITS)   // 128
#define QPT 8
#define THREADS 256

// ws layout: [partial: 2*B*SPLITS*NPTS f = 8 MiB][sums32: 32 f][h1p: 64*256 f][nlls: 8 f][cnt: 1 u32]
// partial[((dir*B+b)*SPLITS + split)*NPTS + q]
// sums32[(dir*B+b)*2 + {0:min,1:soft}]   — atomic-only access in D2
// D1->D2 handoff relies on the dispatch boundary (runtime cache maintenance);
// within D2 all cross-block traffic is device-scope atomic RMW (no fences — R5 lesson).

__device__ __forceinline__ void final_combine_atomic(
    float* sums32, float* nlls, const float* w, float* out) {
  float chamfer = 0.f, prec = 0.f, rec = 0.f, dsw = 0.f, dom = 0.f;
  for (int b = 0; b < B; ++b) {
    float sa  = atomicAdd(&sums32[(0 * B + b) * 2 + 0], 0.f);
    float ssa = atomicAdd(&sums32[(0 * B + b) * 2 + 1], 0.f);
    float sb  = atomicAdd(&sums32[(1 * B + b) * 2 + 0], 0.f);
    float ssb = atomicAdd(&sums32[(1 * B + b) * 2 + 1], 0.f);
    float nb  = atomicAdd(&nlls[b], 0.f);
    float ma = sa / 4096.f, mb = sb / 4096.f;
    float p = ssa / 4096.f, r = ssb / 4096.f;
    chamfer += ma + mb;
    prec += p; rec += r;
    float f_i = 2.f * p * r / (p + r + 1e-8f);
    float loss_i = ma + mb + 0.1f * (1.f - f_i);
    dsw += w[b] * loss_i;
    dom += nb;
  }
  chamfer *= (1.f / B); prec *= (1.f / B); rec *= (1.f / B);
  dsw *= (1.f / B); dom *= (1.f / B);
  float fscore = 2.f * prec * rec / (prec + rec + 1e-8f);
  float task = chamfer + 0.1f * (1.f - fscore);
  out[0] = 1.0f * task + 0.1f * dom + dsw;
}

// ======== D1: 1024 chamfer + 64 MLP-L1 + 1 init block ===================
// dist(q,t) = |q|^2 + 2*s,  s = |t|^2/2 - q.t
__global__ __launch_bounds__(THREADS, 4) void k_main(
    const float* __restrict__ pred, const float* __restrict__ targ,
    const float* __restrict__ x, const float* __restrict__ W1,
    float* __restrict__ partial, float* __restrict__ sums32,
    float* __restrict__ h1p, unsigned int* __restrict__ cnt) {
  int id = blockIdx.x, tid = threadIdx.x;
  __shared__ float4 sbuf4[REFS];          // 2 KB arena

  if (id >= 1024) {
    if (id == 1088) {                     // init block (plain stores; dispatch
      if (tid < 32) sums32[tid] = 0.f;    //  boundary publishes them for D2)
      if (tid == 0) cnt[0] = 0u;
      return;
    }
    // ---- MLP layer-1 partials: h1p[(b*8+kc)*256+j] = sum_k x[b,k]W1[k,j]
    int lid = id - 1024;
    int b = lid >> 3, kc = lid & 7;
    float* xs = (float*)sbuf4;
    if (tid < 64) xs[tid] = x[b * 512 + kc * 64 + tid];
    __syncthreads();
    float acc = 0.f;
    const float* w = W1 + (size_t)(kc * 64) * 256 + tid;
#pragma unroll 8
    for (int k = 0; k < 64; ++k) acc = fmaf(xs[k], w[k * 256], acc);
    h1p[(b * 8 + kc) * 256 + tid] = acc;
    return;
  }

  // ---------------- chamfer split-partial mins ----------------
  int split  = id & (SPLITS - 1);
  int qchunk = (id >> LOG2S) & 1;
  int b      = (id >> (LOG2S + 1)) & 7;
  int dir    = id >> (LOG2S + 4);
  const float* qp = dir ? targ : pred;
  const float* rp = dir ? pred : targ;

  float4* refs = sbuf4;
  const float* rb = rp + ((size_t)b * NPTS + (size_t)split * REFS) * 3;
  for (int i = tid; i < REFS; i += THREADS) {
    float xx = rb[i * 3 + 0], yy = rb[i * 3 + 1], zz = rb[i * 3 + 2];
    refs[i] = make_float4(xx, yy, zz, 0.5f * (xx * xx + yy * yy + zz * zz));
  }
  __syncthreads();

  const float* qb = qp + (size_t)b * NPTS * 3;
  int q0 = qchunk * (QPT * THREADS) + tid;
  float qx[QPT], qy[QPT], qz[QPT], vmin[QPT];
#pragma unroll
  for (int i = 0; i < QPT; ++i) {
    int q = q0 + i * THREADS;
    qx[i] = qb[q * 3 + 0];
    qy[i] = qb[q * 3 + 1];
    qz[i] = qb[q * 3 + 2];
    vmin[i] = 3.4e38f;
  }

  for (int j = 0; j < REFS; j += 4) {
    float4 t0 = refs[j + 0], t1 = refs[j + 1];
    float4 t2 = refs[j + 2], t3 = refs[j + 3];
    // pin tiles in VGPRs — stop rematerialization of LDS reads per query
    asm volatile("" : "+v"(t0.x), "+v"(t0.y), "+v"(t0.z), "+v"(t0.w),
                      "+v"(t1.x), "+v"(t1.y), "+v"(t1.z), "+v"(t1.w),
                      "+v"(t2.x), "+v"(t2.y), "+v"(t2.z), "+v"(t2.w),
                      "+v"(t3.x), "+v"(t3.y), "+v"(t3.z), "+v"(t3.w));
#pragma unroll
    for (int i = 0; i < QPT; ++i) {
      float s0 = fmaf(-qx[i], t0.x, fmaf(-qy[i], t0.y, fmaf(-qz[i], t0.z, t0.w)));
      float s1 = fmaf(-qx[i], t1.x, fmaf(-qy[i], t1.y, fmaf(-qz[i], t1.z, t1.w)));
      float s2 = fmaf(-qx[i], t2.x, fmaf(-qy[i], t2.y, fmaf(-qz[i], t2.z, t2.w)));
      float s3 = fmaf(-qx[i], t3.x, fmaf(-qy[i], t3.y, fmaf(-qz[i], t3.z, t3.w)));
      vmin[i] = fminf(fminf(vmin[i], fminf(s0, s1)), fminf(s2, s3));
    }
  }

  size_t base = (((size_t)dir * B + b) * SPLITS + split) * NPTS;
#pragma unroll
  for (int i = 0; i < QPT; ++i) {
    float qn = fmaf(qx[i], qx[i], fmaf(qy[i], qy[i], qz[i] * qz[i]));
    partial[base + q0 + i * THREADS] = fmaf(2.f, vmin[i], qn);
  }
}

// ======== D2: 128 reduce + 1 MLP(L2/L3/NLL) + fence-free ticket =========
__global__ __launch_bounds__(THREADS) void k_finish(
    const float* __restrict__ partial, float* __restrict__ sums32,
    const float* __restrict__ h1p, const float* __restrict__ b1,
    const float* __restrict__ W2, const float* __restrict__ b2,
    const float* __restrict__ W3, const float* __restrict__ b3,
    const int* __restrict__ labels, const float* __restrict__ wgt,
    float* __restrict__ nlls, unsigned int* __restrict__ cnt,
    float* __restrict__ out) {
  int id = blockIdx.x, tid = threadIdx.x;
  __shared__ float sbuf[4160];     // 16.6 KB arena (MLP); reducers use a corner
  __shared__ unsigned int sflag;

  if (id < 128) {
    // ---- reduce: min over SPLITS, sum min & exp over 512 q's ----
    int chunk = id & 7;
    int b   = (id >> 3) & 7;
    int dir = id >> 6;
    size_t pb = (size_t)(dir * B + b) * SPLITS * NPTS;
    float s_min = 0.f, s_soft = 0.f;
#pragma unroll
    for (int i = 0; i < 2; ++i) {
      int q = chunk * 512 + i * 256 + tid;
      float m = 3.4e38f;
#pragma unroll
      for (int s = 0; s < SPLITS; ++s)
        m = fminf(m, partial[pb + (size_t)s * NPTS + q]);
      s_min  += m;
      s_soft += __expf(-5000.0f * m);   // 1/(2*sigma^2)
    }
    for (int off = 32; off > 0; off >>= 1) {
      s_min  += __shfl_down(s_min,  off);
      s_soft += __shfl_down(s_soft, off);
    }
    int wave = tid >> 6, lane = tid & 63;
    if (lane == 0) { sbuf[wave * 2] = s_min; sbuf[wave * 2 + 1] = s_soft; }
    __syncthreads();
    if (tid == 0) {
      float a = 0.f, c = 0.f;
      for (int w = 0; w < 4; ++w) { a += sbuf[w * 2]; c += sbuf[w * 2 + 1]; }
      float o0 = atomicAdd(&sums32[(dir * B + b) * 2 + 0], a);
      float o1 = atomicAdd(&sums32[(dir * B + b) * 2 + 1], c);
      asm volatile("" :: "v"(o0), "v"(o1));   // drain RMWs before ticket
      unsigned int old = atomicAdd(cnt, 1u);
      sflag = (old == 128u) ? 1u : 0u;        // 129 participants
    }
    __syncthreads();
    if (sflag && tid == 0) final_combine_atomic(sums32, nlls, wgt, out);
    return;
  }

  // ---- MLP block (id==128): L2 + L3 + NLL ----
  float* h1s = sbuf;            // 2048
  float* pp  = sbuf + 2048;     // 2048
  float* lg  = sbuf + 4096;     // 48
  for (int i = tid; i < 2048; i += THREADS) {
    int bb = i >> 8, j = i & 255;
    float a = b1[j];
#pragma unroll
    for (int kc = 0; kc < 8; ++kc) a += h1p[(bb * 8 + kc) * 256 + j];
    h1s[i] = fmaxf(a, 0.f);
  }
  __syncthreads();
  {
    int j = tid & 127, half = tid >> 7;
    float acc[8];
#pragma unroll
    for (int bb = 0; bb < 8; ++bb) acc[bb] = 0.f;
    const float* w = W2 + (size_t)(half * 128) * 128 + j;
    for (int k = 0; k < 128; ++k) {
      float wv = w[k * 128];
      int kk = half * 128 + k;
#pragma unroll
      for (int bb = 0; bb < 8; ++bb)
        acc[bb] = fmaf(h1s[bb * 256 + kk], wv, acc[bb]);
    }
#pragma unroll
    for (int bb = 0; bb < 8; ++bb) pp[(half * 8 + bb) * 128 + j] = acc[bb];
  }
  __syncthreads();
  float* h2s = sbuf;            // reuse (h1s dead)
  for (int i = tid; i < 1024; i += THREADS) {
    int bb = i >> 7, j = i & 127;
    float a = b2[j] + pp[(0 * 8 + bb) * 128 + j] + pp[(1 * 8 + bb) * 128 + j];
    h2s[i] = fmaxf(a, 0.f);
  }
  __syncthreads();
  if (tid < 48) {
    int bb = tid / 6, d = tid % 6;
    float acc = b3[d];
#pragma unroll 8
    for (int k = 0; k < 128; ++k) acc = fmaf(h2s[bb * 128 + k], W3[k * 6 + d], acc);
    lg[tid] = acc;
  }
  __syncthreads();
  if (tid < 8) {
    int bb = tid;
    float mx = lg[bb * 6];
    for (int d = 1; d < 6; ++d) mx = fmaxf(mx, lg[bb * 6 + d]);
    float se = 0.f;
    for (int d = 0; d < 6; ++d) se += __expf(lg[bb * 6 + d] - mx);
    int lab = labels[bb];
    float old = atomicExch(&nlls[bb], -(lg[bb * 6 + lab] - mx - __logf(se)));
    asm volatile("" :: "v"(old));            // drain before ticket
  }
  __syncthreads();
  if (tid == 0) {
    unsigned int old = atomicAdd(cnt, 1u);
    sflag = (old == 128u) ? 1u : 0u;
  }
  __syncthreads();
  if (sflag && tid == 0) final_combine_atomic(sums32, nlls, wgt, out);
}

extern "C" void kernel_launch(void* const* d_in, const int* in_sizes, int n_in,
                              void* d_out, int out_size, void* d_ws, size_t ws_size,
                              hipStream_t stream) {
  const float* pred   = (const float*)d_in[0];
  const float* targ   = (const float*)d_in[1];
  const float* x      = (const float*)d_in[2];
  const float* wgt    = (const float*)d_in[3];
  const float* W1     = (const float*)d_in[4];
  const float* b1     = (const float*)d_in[5];
  const float* W2     = (const float*)d_in[6];
  const float* b2     = (const float*)d_in[7];
  const float* W3     = (const float*)d_in[8];
  const float* b3     = (const float*)d_in[9];
  const int*   labels = (const int*)d_in[10];
  float* out = (float*)d_out;
  char* ws = (char*)d_ws;

  float* partial = (float*)ws;
  float* sums32  = partial + (size_t)2 * B * SPLITS * NPTS;
  float* h1p     = sums32 + 32;
  float* nlls    = h1p + 64 * 256;
  unsigned int* cnt = (unsigned int*)(nlls + 8);

  hipLaunchKernelGGL(k_main, dim3(1089), dim3(THREADS), 0, stream,
                     pred, targ, x, W1, partial, sums32, h1p, cnt);
  hipLaunchKernelGGL(k_finish, dim3(129), dim3(THREADS), 0, stream,
                     partial, sums32, h1p, b1, W2, b2, W3, b3, labels, wgt,
                     nlls, cnt, out);
}

// Round 7
// 123.527 us; speedup vs baseline: 3.1183x; 1.0277x over previous
//
#include <hip/hip_runtime.h>
#include <math.h>

#define B 8
#define NPTS 4096
#define SPLITS 32
#define LOG2S 5
#define REFS (NPTS / SPLITS)   // 128
#define QPT 8
#define THREADS 256

// ws layout: [partial: 2*B*SPLITS*NPTS f = 8 MiB][sums32: 32 f][h1p: 64*256 f][nlls: 8 f][cnt: 1 u32]
// partial[((dir*B+b)*SPLITS + split)*NPTS + q]
// sums32[(dir*B+b)*2 + {0:min,1:soft}]   — atomic-only access in D2
// D1->D2 handoff relies on the dispatch boundary; within D2 all cross-block
// traffic is device-scope atomic RMW only (no __threadfence — R5 lesson: each
// fence costs an L2 writeback, 2048 of them = 320 us).

__device__ __forceinline__ void final_combine_atomic(
    float* sums32, float* nlls, const float* w, float* out) {
  float chamfer = 0.f, prec = 0.f, rec = 0.f, dsw = 0.f, dom = 0.f;
  for (int b = 0; b < B; ++b) {
    float sa  = atomicAdd(&sums32[(0 * B + b) * 2 + 0], 0.f);
    float ssa = atomicAdd(&sums32[(0 * B + b) * 2 + 1], 0.f);
    float sb  = atomicAdd(&sums32[(1 * B + b) * 2 + 0], 0.f);
    float ssb = atomicAdd(&sums32[(1 * B + b) * 2 + 1], 0.f);
    float nb  = atomicAdd(&nlls[b], 0.f);
    float ma = sa / 4096.f, mb = sb / 4096.f;
    float p = ssa / 4096.f, r = ssb / 4096.f;
    chamfer += ma + mb;
    prec += p; rec += r;
    float f_i = 2.f * p * r / (p + r + 1e-8f);
    float loss_i = ma + mb + 0.1f * (1.f - f_i);
    dsw += w[b] * loss_i;
    dom += nb;
  }
  chamfer *= (1.f / B); prec *= (1.f / B); rec *= (1.f / B);
  dsw *= (1.f / B); dom *= (1.f / B);
  float fscore = 2.f * prec * rec / (prec + rec + 1e-8f);
  float task = chamfer + 0.1f * (1.f - fscore);
  out[0] = 1.0f * task + 0.1f * dom + dsw;
}

// ======== D1: 1024 chamfer + 64 MLP-L1 + 1 init block ===================
// dist(q,t) = |q|^2 + 2*s,  s = |t|^2/2 - q.t
__global__ __launch_bounds__(THREADS, 4) void k_main(
    const float* __restrict__ pred, const float* __restrict__ targ,
    const float* __restrict__ x, const float* __restrict__ W1,
    float* __restrict__ partial, float* __restrict__ sums32,
    float* __restrict__ h1p, unsigned int* __restrict__ cnt) {
  int id = blockIdx.x, tid = threadIdx.x;
  __shared__ float4 sbuf4[REFS];          // 2 KB arena

  if (id >= 1024) {
    if (id == 1088) {                     // init block (plain stores; dispatch
      if (tid < 32) sums32[tid] = 0.f;    //  boundary publishes them for D2)
      if (tid == 0) cnt[0] = 0u;
      return;
    }
    // ---- MLP layer-1 partials: h1p[(b*8+kc)*256+j] = sum_k x[b,k]W1[k,j]
    int lid = id - 1024;
    int b = lid >> 3, kc = lid & 7;
    float* xs = (float*)sbuf4;
    if (tid < 64) xs[tid] = x[b * 512 + kc * 64 + tid];
    __syncthreads();
    float acc = 0.f;
    const float* w = W1 + (size_t)(kc * 64) * 256 + tid;
#pragma unroll 8
    for (int k = 0; k < 64; ++k) acc = fmaf(xs[k], w[k * 256], acc);
    h1p[(b * 8 + kc) * 256 + tid] = acc;
    return;
  }

  // ---------------- chamfer split-partial mins ----------------
  int split  = id & (SPLITS - 1);
  int qchunk = (id >> LOG2S) & 1;
  int b      = (id >> (LOG2S + 1)) & 7;
  int dir    = id >> (LOG2S + 4);
  const float* qp = dir ? targ : pred;
  const float* rp = dir ? pred : targ;

  float4* refs = sbuf4;
  const float* rb = rp + ((size_t)b * NPTS + (size_t)split * REFS) * 3;
  for (int i = tid; i < REFS; i += THREADS) {
    float xx = rb[i * 3 + 0], yy = rb[i * 3 + 1], zz = rb[i * 3 + 2];
    refs[i] = make_float4(xx, yy, zz, 0.5f * (xx * xx + yy * yy + zz * zz));
  }
  __syncthreads();

  const float* qb = qp + (size_t)b * NPTS * 3;
  int q0 = qchunk * (QPT * THREADS) + tid;
  float qx[QPT], qy[QPT], qz[QPT], vmin[QPT];
#pragma unroll
  for (int i = 0; i < QPT; ++i) {
    int q = q0 + i * THREADS;
    qx[i] = qb[q * 3 + 0];
    qy[i] = qb[q * 3 + 1];
    qz[i] = qb[q * 3 + 2];
    vmin[i] = 3.4e38f;
  }

  // software-pipelined: prefetch next 4 refs, compute on current 4.
  float4 t0 = refs[0], t1 = refs[1], t2 = refs[2], t3 = refs[3];
  asm volatile("" : "+v"(t0.x), "+v"(t0.y), "+v"(t0.z), "+v"(t0.w),
                    "+v"(t1.x), "+v"(t1.y), "+v"(t1.z), "+v"(t1.w),
                    "+v"(t2.x), "+v"(t2.y), "+v"(t2.z), "+v"(t2.w),
                    "+v"(t3.x), "+v"(t3.y), "+v"(t3.z), "+v"(t3.w));
  for (int j = 0; j < REFS; j += 4) {
    int jn = (j + 4) & (REFS - 1);        // wraps to 0 on last iter (harmless)
    float4 n0 = refs[jn + 0], n1 = refs[jn + 1];
    float4 n2 = refs[jn + 2], n3 = refs[jn + 3];
#pragma unroll
    for (int i = 0; i < QPT; ++i) {
      float s0 = fmaf(-qx[i], t0.x, fmaf(-qy[i], t0.y, fmaf(-qz[i], t0.z, t0.w)));
      float s1 = fmaf(-qx[i], t1.x, fmaf(-qy[i], t1.y, fmaf(-qz[i], t1.z, t1.w)));
      float s2 = fmaf(-qx[i], t2.x, fmaf(-qy[i], t2.y, fmaf(-qz[i], t2.z, t2.w)));
      float s3 = fmaf(-qx[i], t3.x, fmaf(-qy[i], t3.y, fmaf(-qz[i], t3.z, t3.w)));
      vmin[i] = fminf(fminf(vmin[i], fminf(s0, s1)), fminf(s2, s3));
    }
    // pin the prefetched tiles AFTER compute: the lgkmcnt wait lands here,
    // overlapped by the 128 fma/min ops above (R6 lesson: pin-before-compute
    // serializes the ds_read latency into every iteration).
    asm volatile("" : "+v"(n0.x), "+v"(n0.y), "+v"(n0.z), "+v"(n0.w),
                      "+v"(n1.x), "+v"(n1.y), "+v"(n1.z), "+v"(n1.w),
                      "+v"(n2.x), "+v"(n2.y), "+v"(n2.z), "+v"(n2.w),
                      "+v"(n3.x), "+v"(n3.y), "+v"(n3.z), "+v"(n3.w));
    t0 = n0; t1 = n1; t2 = n2; t3 = n3;
  }

  size_t base = (((size_t)dir * B + b) * SPLITS + split) * NPTS;
#pragma unroll
  for (int i = 0; i < QPT; ++i) {
    float qn = fmaf(qx[i], qx[i], fmaf(qy[i], qy[i], qz[i] * qz[i]));
    partial[base + q0 + i * THREADS] = fmaf(2.f, vmin[i], qn);
  }
}

// ======== D2: 64 vec-reduce + 1 MLP(L2/L3/NLL) + fence-free ticket ======
__global__ __launch_bounds__(THREADS) void k_finish(
    const float* __restrict__ partial, float* __restrict__ sums32,
    const float* __restrict__ h1p, const float* __restrict__ b1,
    const float* __restrict__ W2, const float* __restrict__ b2,
    const float* __restrict__ W3, const float* __restrict__ b3,
    const int* __restrict__ labels, const float* __restrict__ wgt,
    float* __restrict__ nlls, unsigned int* __restrict__ cnt,
    float* __restrict__ out) {
  int id = blockIdx.x, tid = threadIdx.x;
  __shared__ float sbuf[4160];     // 16.6 KB arena (MLP); reducers use a corner
  __shared__ unsigned int sflag;

  if (id < 64) {
    // ---- q-major vectorized reduce: thread owns 4 consecutive q's;
    //      32 independent float4 loads over splits (latency-pipelined).
    int dirb  = id >> 2;                 // dir*8+b
    int chunk = id & 3;
    const float* pbase = partial + (size_t)dirb * SPLITS * NPTS
                       + (size_t)chunk * 1024 + (size_t)tid * 4;
    float4 m4 = make_float4(3.4e38f, 3.4e38f, 3.4e38f, 3.4e38f);
#pragma unroll
    for (int s = 0; s < SPLITS; ++s) {
      float4 v = *(const float4*)(pbase + (size_t)s * NPTS);
      m4.x = fminf(m4.x, v.x); m4.y = fminf(m4.y, v.y);
      m4.z = fminf(m4.z, v.z); m4.w = fminf(m4.w, v.w);
    }
    float s_min  = (m4.x + m4.y) + (m4.z + m4.w);
    float s_soft = (__expf(-5000.0f * m4.x) + __expf(-5000.0f * m4.y))
                 + (__expf(-5000.0f * m4.z) + __expf(-5000.0f * m4.w));
    for (int off = 32; off > 0; off >>= 1) {
      s_min  += __shfl_down(s_min,  off);
      s_soft += __shfl_down(s_soft, off);
    }
    int wave = tid >> 6, lane = tid & 63;
    if (lane == 0) { sbuf[wave * 2] = s_min; sbuf[wave * 2 + 1] = s_soft; }
    __syncthreads();
    if (tid == 0) {
      float a = 0.f, c = 0.f;
      for (int w = 0; w < 4; ++w) { a += sbuf[w * 2]; c += sbuf[w * 2 + 1]; }
      float o0 = atomicAdd(&sums32[dirb * 2 + 0], a);
      float o1 = atomicAdd(&sums32[dirb * 2 + 1], c);
      asm volatile("" :: "v"(o0), "v"(o1));   // drain RMWs before ticket
      unsigned int old = atomicAdd(cnt, 1u);
      sflag = (old == 64u) ? 1u : 0u;         // 65 participants
    }
    __syncthreads();
    if (sflag && tid == 0) final_combine_atomic(sums32, nlls, wgt, out);
    return;
  }

  // ---- MLP block (id==64): L2 + L3 + NLL ----
  float* h1s = sbuf;            // 2048
  float* pp  = sbuf + 2048;     // 2048
  float* lg  = sbuf + 4096;     // 48
  for (int i = tid; i < 2048; i += THREADS) {
    int bb = i >> 8, j = i & 255;
    float a = b1[j];
#pragma unroll
    for (int kc = 0; kc < 8; ++kc) a += h1p[(bb * 8 + kc) * 256 + j];
    h1s[i] = fmaxf(a, 0.f);
  }
  __syncthreads();
  {
    int j = tid & 127, half = tid >> 7;
    float acc[8];
#pragma unroll
    for (int bb = 0; bb < 8; ++bb) acc[bb] = 0.f;
    const float* w = W2 + (size_t)(half * 128) * 128 + j;
    for (int k = 0; k < 128; ++k) {
      float wv = w[k * 128];
      int kk = half * 128 + k;
#pragma unroll
      for (int bb = 0; bb < 8; ++bb)
        acc[bb] = fmaf(h1s[bb * 256 + kk], wv, acc[bb]);
    }
#pragma unroll
    for (int bb = 0; bb < 8; ++bb) pp[(half * 8 + bb) * 128 + j] = acc[bb];
  }
  __syncthreads();
  float* h2s = sbuf;            // reuse (h1s dead)
  for (int i = tid; i < 1024; i += THREADS) {
    int bb = i >> 7, j = i & 127;
    float a = b2[j] + pp[(0 * 8 + bb) * 128 + j] + pp[(1 * 8 + bb) * 128 + j];
    h2s[i] = fmaxf(a, 0.f);
  }
  __syncthreads();
  if (tid < 48) {
    int bb = tid / 6, d = tid % 6;
    float acc = b3[d];
#pragma unroll 8
    for (int k = 0; k < 128; ++k) acc = fmaf(h2s[bb * 128 + k], W3[k * 6 + d], acc);
    lg[tid] = acc;
  }
  __syncthreads();
  if (tid < 8) {
    int bb = tid;
    float mx = lg[bb * 6];
    for (int d = 1; d < 6; ++d) mx = fmaxf(mx, lg[bb * 6 + d]);
    float se = 0.f;
    for (int d = 0; d < 6; ++d) se += __expf(lg[bb * 6 + d] - mx);
    int lab = labels[bb];
    float old = atomicExch(&nlls[bb], -(lg[bb * 6 + lab] - mx - __logf(se)));
    asm volatile("" :: "v"(old));            // drain before ticket
  }
  __syncthreads();
  if (tid == 0) {
    unsigned int old = atomicAdd(cnt, 1u);
    sflag = (old == 64u) ? 1u : 0u;
  }
  __syncthreads();
  if (sflag && tid == 0) final_combine_atomic(sums32, nlls, wgt, out);
}

extern "C" void kernel_launch(void* const* d_in, const int* in_sizes, int n_in,
                              void* d_out, int out_size, void* d_ws, size_t ws_size,
                              hipStream_t stream) {
  const float* pred   = (const float*)d_in[0];
  const float* targ   = (const float*)d_in[1];
  const float* x      = (const float*)d_in[2];
  const float* wgt    = (const float*)d_in[3];
  const float* W1     = (const float*)d_in[4];
  const float* b1     = (const float*)d_in[5];
  const float* W2     = (const float*)d_in[6];
  const float* b2     = (const float*)d_in[7];
  const float* W3     = (const float*)d_in[8];
  const float* b3     = (const float*)d_in[9];
  const int*   labels = (const int*)d_in[10];
  float* out = (float*)d_out;
  char* ws = (char*)d_ws;

  float* partial = (float*)ws;
  float* sums32  = partial + (size_t)2 * B * SPLITS * NPTS;
  float* h1p     = sums32 + 32;
  float* nlls    = h1p + 64 * 256;
  unsigned int* cnt = (unsigned int*)(nlls + 8);

  hipLaunchKernelGGL(k_main, dim3(1089), dim3(THREADS), 0, stream,
                     pred, targ, x, W1, partial, sums32, h1p, cnt);
  hipLaunchKernelGGL(k_finish, dim3(65), dim3(THREADS), 0, stream,
                     partial, sums32, h1p, b1, W2, b2, W3, b3, labels, wgt,
                     nlls, cnt, out);
}

// Round 8
// 114.060 us; speedup vs baseline: 3.3771x; 1.0830x over previous
//
#include <hip/hip_runtime.h>
#include <math.h>

#define B 8
#define NPTS 4096
#define QPT 16          // queries per thread in chamfer (all 4096 per block col)
#define THREADS 256

// ws layout: [partial: 2*B*S*NPTS f][sums32: 32 f][h1p: 64*256 f][nlls: 8 f]
// partial[((dir*B+b)*S + split)*NPTS + q]
// sums32[(dir*B+b)*2 + {0:min,1:soft}]  — zeroed in D1, atomicAdd'ed by D2,
// plain-read by D3 (dispatch boundaries publish; no fences — R5 lesson,
// no single-thread atomic-read chains — R7 lesson).

// ======== D1: 16*S chamfer + 64 MLP-L1 + 1 init block ===================
// dist(q,t) = |q|^2 + 2*s,  s = |t|^2/2 - q.t
template<int S, int LOG2S>
__global__ __launch_bounds__(THREADS, 4) void k_main(
    const float* __restrict__ pred, const float* __restrict__ targ,
    const float* __restrict__ x, const float* __restrict__ W1,
    float* __restrict__ partial, float* __restrict__ sums32,
    float* __restrict__ h1p) {
  constexpr int REFS = NPTS / S;
  int id = blockIdx.x, tid = threadIdx.x;
  __shared__ float4 sbuf4[REFS < 64 ? 64 : REFS];

  if (id >= 16 * S) {
    if (id == 16 * S + 64) {              // init block: zero sums32
      if (tid < 32) sums32[tid] = 0.f;
      return;
    }
    // ---- MLP layer-1 partials: h1p[(b*8+kc)*256+j] = sum_k x[b,k]W1[k,j]
    int lid = id - 16 * S;
    int b = lid >> 3, kc = lid & 7;
    float* xs = (float*)sbuf4;
    if (tid < 64) xs[tid] = x[b * 512 + kc * 64 + tid];
    __syncthreads();
    float acc = 0.f;
    const float* w = W1 + (size_t)(kc * 64) * 256 + tid;
#pragma unroll 8
    for (int k = 0; k < 64; ++k) acc = fmaf(xs[k], w[k * 256], acc);
    h1p[(b * 8 + kc) * 256 + tid] = acc;
    return;
  }

  // ---------------- chamfer split-partial mins ----------------
  int split = id & (S - 1);
  int b     = (id >> LOG2S) & 7;
  int dir   = id >> (LOG2S + 3);
  const float* qp = dir ? targ : pred;
  const float* rp = dir ? pred : targ;

  float4* refs = sbuf4;
  const float* rb = rp + ((size_t)b * NPTS + (size_t)split * REFS) * 3;
  for (int i = tid; i < REFS; i += THREADS) {
    float xx = rb[i * 3 + 0], yy = rb[i * 3 + 1], zz = rb[i * 3 + 2];
    refs[i] = make_float4(xx, yy, zz, 0.5f * (xx * xx + yy * yy + zz * zz));
  }
  __syncthreads();

  const float* qb = qp + (size_t)b * NPTS * 3;
  float qx[QPT], qy[QPT], qz[QPT], vmin[QPT];
#pragma unroll
  for (int i = 0; i < QPT; ++i) {
    int q = tid + i * THREADS;
    qx[i] = qb[q * 3 + 0];
    qy[i] = qb[q * 3 + 1];
    qz[i] = qb[q * 3 + 2];
    vmin[i] = 3.4e38f;
  }

  for (int j = 0; j < REFS; j += 4) {
    float4 t0 = refs[j + 0], t1 = refs[j + 1];
    float4 t2 = refs[j + 2], t3 = refs[j + 3];
    // anti-remat pin only (R4 structure): no prefetch copies, no 2nd asm.
    asm volatile("" : "+v"(t0.x), "+v"(t0.y), "+v"(t0.z), "+v"(t0.w),
                      "+v"(t1.x), "+v"(t1.y), "+v"(t1.z), "+v"(t1.w),
                      "+v"(t2.x), "+v"(t2.y), "+v"(t2.z), "+v"(t2.w),
                      "+v"(t3.x), "+v"(t3.y), "+v"(t3.z), "+v"(t3.w));
#pragma unroll
    for (int i = 0; i < QPT; ++i) {
      float s0 = fmaf(-qx[i], t0.x, fmaf(-qy[i], t0.y, fmaf(-qz[i], t0.z, t0.w)));
      float s1 = fmaf(-qx[i], t1.x, fmaf(-qy[i], t1.y, fmaf(-qz[i], t1.z, t1.w)));
      float s2 = fmaf(-qx[i], t2.x, fmaf(-qy[i], t2.y, fmaf(-qz[i], t2.z, t2.w)));
      float s3 = fmaf(-qx[i], t3.x, fmaf(-qy[i], t3.y, fmaf(-qz[i], t3.z, t3.w)));
      vmin[i] = fminf(fminf(vmin[i], fminf(s0, s1)), fminf(s2, s3));
    }
  }

  size_t base = (((size_t)dir * B + b) * S + split) * NPTS;
#pragma unroll
  for (int i = 0; i < QPT; ++i) {
    float qn = fmaf(qx[i], qx[i], fmaf(qy[i], qy[i], qz[i] * qz[i]));
    partial[base + tid + i * THREADS] = fmaf(2.f, vmin[i], qn);
  }
}

// ======== D2: 64 vec-reduce blocks + 1 MLP(L2/L3/NLL) block =============
template<int S>
__global__ __launch_bounds__(THREADS) void k_finish(
    const float* __restrict__ partial, float* __restrict__ sums32,
    const float* __restrict__ h1p, const float* __restrict__ b1,
    const float* __restrict__ W2, const float* __restrict__ b2,
    const float* __restrict__ W3, const float* __restrict__ b3,
    const int* __restrict__ labels, float* __restrict__ nlls) {
  int id = blockIdx.x, tid = threadIdx.x;
  __shared__ float sbuf[4160];     // 16.6 KB arena

  if (id < 64) {
    // q-major vectorized reduce: thread owns 4 consecutive q's; S independent
    // float4 loads pipeline on vmcnt (R6 lesson: scalar strided was 30x off).
    int dirb  = id >> 2;                 // dir*8+b
    int chunk = id & 3;
    const float* pbase = partial + (size_t)dirb * S * NPTS
                       + (size_t)chunk * 1024 + (size_t)tid * 4;
    float4 m4 = make_float4(3.4e38f, 3.4e38f, 3.4e38f, 3.4e38f);
#pragma unroll 8
    for (int s = 0; s < S; ++s) {
      float4 v = *(const float4*)(pbase + (size_t)s * NPTS);
      m4.x = fminf(m4.x, v.x); m4.y = fminf(m4.y, v.y);
      m4.z = fminf(m4.z, v.z); m4.w = fminf(m4.w, v.w);
    }
    float s_min  = (m4.x + m4.y) + (m4.z + m4.w);
    float s_soft = (__expf(-5000.0f * m4.x) + __expf(-5000.0f * m4.y))
                 + (__expf(-5000.0f * m4.z) + __expf(-5000.0f * m4.w));
    for (int off = 32; off > 0; off >>= 1) {
      s_min  += __shfl_down(s_min,  off);
      s_soft += __shfl_down(s_soft, off);
    }
    int wave = tid >> 6, lane = tid & 63;
    if (lane == 0) { sbuf[wave * 2] = s_min; sbuf[wave * 2 + 1] = s_soft; }
    __syncthreads();
    if (tid == 0) {
      float a = 0.f, c = 0.f;
      for (int w = 0; w < 4; ++w) { a += sbuf[w * 2]; c += sbuf[w * 2 + 1]; }
      atomicAdd(&sums32[dirb * 2 + 0], a);
      atomicAdd(&sums32[dirb * 2 + 1], c);
    }
    return;
  }

  // ---- MLP block (id==64): L2 + L3 + NLL (plain stores; D3 reads after
  // the dispatch boundary) ----
  float* h1s = sbuf;            // 2048
  float* pp  = sbuf + 2048;     // 2048
  float* lg  = sbuf + 4096;     // 48
  for (int i = tid; i < 2048; i += THREADS) {
    int bb = i >> 8, j = i & 255;
    float a = b1[j];
#pragma unroll
    for (int kc = 0; kc < 8; ++kc) a += h1p[(bb * 8 + kc) * 256 + j];
    h1s[i] = fmaxf(a, 0.f);
  }
  __syncthreads();
  {
    int j = tid & 127, half = tid >> 7;
    float acc[8];
#pragma unroll
    for (int bb = 0; bb < 8; ++bb) acc[bb] = 0.f;
    const float* w = W2 + (size_t)(half * 128) * 128 + j;
    for (int k = 0; k < 128; ++k) {
      float wv = w[k * 128];
      int kk = half * 128 + k;
#pragma unroll
      for (int bb = 0; bb < 8; ++bb)
        acc[bb] = fmaf(h1s[bb * 256 + kk], wv, acc[bb]);
    }
#pragma unroll
    for (int bb = 0; bb < 8; ++bb) pp[(half * 8 + bb) * 128 + j] = acc[bb];
  }
  __syncthreads();
  float* h2s = sbuf;            // reuse (h1s dead)
  for (int i = tid; i < 1024; i += THREADS) {
    int bb = i >> 7, j = i & 127;
    float a = b2[j] + pp[(0 * 8 + bb) * 128 + j] + pp[(1 * 8 + bb) * 128 + j];
    h2s[i] = fmaxf(a, 0.f);
  }
  __syncthreads();
  if (tid < 48) {
    int bb = tid / 6, d = tid % 6;
    float acc = b3[d];
#pragma unroll 8
    for (int k = 0; k < 128; ++k) acc = fmaf(h2s[bb * 128 + k], W3[k * 6 + d], acc);
    lg[tid] = acc;
  }
  __syncthreads();
  if (tid < 8) {
    int bb = tid;
    float mx = lg[bb * 6];
    for (int d = 1; d < 6; ++d) mx = fmaxf(mx, lg[bb * 6 + d]);
    float se = 0.f;
    for (int d = 0; d < 6; ++d) se += __expf(lg[bb * 6 + d] - mx);
    int lab = labels[bb];
    nlls[bb] = -(lg[bb * 6 + lab] - mx - __logf(se));
  }
}

// ======== D3: final combine, 1 block, plain loads =======================
__global__ __launch_bounds__(64) void k_combine(
    const float* __restrict__ sums32, const float* __restrict__ nlls,
    const float* __restrict__ w, float* __restrict__ out) {
  if (threadIdx.x != 0) return;
  float chamfer = 0.f, prec = 0.f, rec = 0.f, dsw = 0.f, dom = 0.f;
  for (int b = 0; b < B; ++b) {
    float sa  = sums32[(0 * B + b) * 2 + 0];
    float ssa = sums32[(0 * B + b) * 2 + 1];
    float sb  = sums32[(1 * B + b) * 2 + 0];
    float ssb = sums32[(1 * B + b) * 2 + 1];
    float ma = sa / 4096.f, mb = sb / 4096.f;
    float p = ssa / 4096.f, r = ssb / 4096.f;
    chamfer += ma + mb;
    prec += p; rec += r;
    float f_i = 2.f * p * r / (p + r + 1e-8f);
    float loss_i = ma + mb + 0.1f * (1.f - f_i);
    dsw += w[b] * loss_i;
    dom += nlls[b];
  }
  chamfer *= (1.f / B); prec *= (1.f / B); rec *= (1.f / B);
  dsw *= (1.f / B); dom *= (1.f / B);
  float fscore = 2.f * prec * rec / (prec + rec + 1e-8f);
  float task = chamfer + 0.1f * (1.f - fscore);
  out[0] = 1.0f * task + 0.1f * dom + dsw;
}

template<int S, int LOG2S>
static void run_pipeline(const float* pred, const float* targ, const float* x,
                         const float* wgt, const float* W1, const float* b1,
                         const float* W2, const float* b2, const float* W3,
                         const float* b3, const int* labels, float* out,
                         char* ws, hipStream_t stream) {
  float* partial = (float*)ws;
  float* sums32  = partial + (size_t)2 * B * S * NPTS;
  float* h1p     = sums32 + 32;
  float* nlls    = h1p + 64 * 256;

  hipLaunchKernelGGL((k_main<S, LOG2S>), dim3(16 * S + 65), dim3(THREADS), 0,
                     stream, pred, targ, x, W1, partial, sums32, h1p);
  hipLaunchKernelGGL((k_finish<S>), dim3(65), dim3(THREADS), 0, stream,
                     partial, sums32, h1p, b1, W2, b2, W3, b3, labels, nlls);
  hipLaunchKernelGGL(k_combine, dim3(1), dim3(64), 0, stream,
                     sums32, nlls, wgt, out);
}

extern "C" void kernel_launch(void* const* d_in, const int* in_sizes, int n_in,
                              void* d_out, int out_size, void* d_ws, size_t ws_size,
                              hipStream_t stream) {
  const float* pred   = (const float*)d_in[0];
  const float* targ   = (const float*)d_in[1];
  const float* x      = (const float*)d_in[2];
  const float* wgt    = (const float*)d_in[3];
  const float* W1     = (const float*)d_in[4];
  const float* b1     = (const float*)d_in[5];
  const float* W2     = (const float*)d_in[6];
  const float* b2     = (const float*)d_in[7];
  const float* W3     = (const float*)d_in[8];
  const float* b3     = (const float*)d_in[9];
  const int*   labels = (const int*)d_in[10];
  float* out = (float*)d_out;
  char* ws = (char*)d_ws;

  auto need = [](int S) {
    return ((size_t)2 * B * S * NPTS + 32 + 64 * 256 + 8) * sizeof(float);
  };
  if (ws_size >= need(64))
    run_pipeline<64, 6>(pred, targ, x, wgt, W1, b1, W2, b2, W3, b3, labels,
                        out, ws, stream);
  else if (ws_size >= need(32))
    run_pipeline<32, 5>(pred, targ, x, wgt, W1, b1, W2, b2, W3, b3, labels,
                        out, ws, stream);
  else
    run_pipeline<16, 4>(pred, targ, x, wgt, W1, b1, W2, b2, W3, b3, labels,
                        out, ws, stream);
}